// Round 1
// baseline (571.469 us; speedup 1.0000x reference)
//
#include <hip/hip_runtime.h>

#define B_N 16
#define C_N 128
#define L_N 9216
#define LT  144      // L_N / 64

// ---------------------------------------------------------------------------
// K0: transpose weights to K-major so GEMM inner loops load contiguous float4
// w1t[c][e] (128x256), w2t[d][o] (128x128)
// ---------------------------------------------------------------------------
__global__ __launch_bounds__(256) void k_wtrans(const float* __restrict__ w1,
                                                const float* __restrict__ w2,
                                                float* __restrict__ w1t,
                                                float* __restrict__ w2t) {
  int i = blockIdx.x * 256 + threadIdx.x;
  if (i < 256 * 128) { int e = i >> 7, c = i & 127; w1t[c * 256 + e] = w1[i]; }
  if (i < 128 * 128) { int o = i >> 7, d = i & 127; w2t[d * 128 + o] = w2[i]; }
}

// ---------------------------------------------------------------------------
// K1: in_proj GEMM.  x:(B,C,L) L-contig.  out: xinpre[b][e][l] (e<128),
// zbuf[b][e-128][l].  Block = (b, 64-l tile), 256 thr, reg tile 4l x 16e.
// ---------------------------------------------------------------------------
__global__ __launch_bounds__(256) void k_inproj(const float* __restrict__ x,
                                                const float* __restrict__ w1t,
                                                float* __restrict__ xinpre,
                                                float* __restrict__ zbuf) {
  __shared__ float xs[128][64];
  int blk = blockIdx.x;
  int b = blk / LT, lt = blk % LT;
  int l0 = lt * 64;
  const float* xb = x + (size_t)b * C_N * L_N;
  int t = threadIdx.x;
#pragma unroll
  for (int i = 0; i < 32; ++i) {
    int idx = t + i * 256;
    int c = idx >> 6, l = idx & 63;
    xs[c][l] = xb[(size_t)c * L_N + l0 + l];
  }
  __syncthreads();
  int tl = t & 15, te = t >> 4;
  float acc[16][4];
#pragma unroll
  for (int j = 0; j < 16; ++j)
#pragma unroll
    for (int q = 0; q < 4; ++q) acc[j][q] = 0.f;
  const float* wbase = w1t + te * 16;
  for (int c = 0; c < 128; ++c) {
    float4 xv = *(const float4*)&xs[c][tl * 4];
    float xq[4] = {xv.x, xv.y, xv.z, xv.w};
    const float* wr = wbase + c * 256;
#pragma unroll
    for (int j4 = 0; j4 < 4; ++j4) {
      float4 wv = *(const float4*)(wr + j4 * 4);
      float wj[4] = {wv.x, wv.y, wv.z, wv.w};
#pragma unroll
      for (int jj = 0; jj < 4; ++jj)
#pragma unroll
        for (int q = 0; q < 4; ++q) acc[j4 * 4 + jj][q] += wj[jj] * xq[q];
    }
  }
  size_t lbase = (size_t)l0 + tl * 4;
#pragma unroll
  for (int j = 0; j < 16; ++j) {
    int e = te * 16 + j;
    float* dst = (e < 128) ? (xinpre + ((size_t)(b * 128 + e)) * L_N)
                           : (zbuf + ((size_t)(b * 128 + e - 128)) * L_N);
    float4 v = make_float4(acc[j][0], acc[j][1], acc[j][2], acc[j][3]);
    *(float4*)(dst + lbase) = v;
  }
}

// ---------------------------------------------------------------------------
// K2: depthwise causal conv (k=4, left pad 3) + SiLU + x_proj (12x128).
// Block = (b, 64-l tile); 4 waves x 32 d each; cross-wave LDS reduce for xdbl.
// ---------------------------------------------------------------------------
__global__ __launch_bounds__(256) void k_conv_xproj(const float* __restrict__ xinpre,
                                                    const float* __restrict__ cw,
                                                    const float* __restrict__ cb,
                                                    const float* __restrict__ xpw,
                                                    float* __restrict__ xin,
                                                    float* __restrict__ xdbl) {
  __shared__ float xs[128][68];
  __shared__ float red[4][12][64];
  int blk = blockIdx.x;
  int b = blk / LT, lt = blk % LT;
  int l0 = lt * 64;
  int t = threadIdx.x;
  for (int idx = t; idx < 128 * 67; idx += 256) {
    int dd = idx / 67, j = idx % 67;
    int l = l0 - 3 + j;
    xs[dd][j] = (l >= 0) ? xinpre[((size_t)(b * 128 + dd)) * L_N + l] : 0.f;
  }
  __syncthreads();
  int lane = t & 63, wv = t >> 6;
  float part[12];
#pragma unroll
  for (int m = 0; m < 12; ++m) part[m] = 0.f;
  for (int dd = 0; dd < 32; ++dd) {
    int d = wv * 32 + dd;
    float v = cb[d] + cw[d * 4 + 0] * xs[d][lane] + cw[d * 4 + 1] * xs[d][lane + 1]
                    + cw[d * 4 + 2] * xs[d][lane + 2] + cw[d * 4 + 3] * xs[d][lane + 3];
    v = v / (1.f + __expf(-v));                    // SiLU
    xin[((size_t)(b * 128 + d)) * L_N + l0 + lane] = v;
#pragma unroll
    for (int m = 0; m < 12; ++m) part[m] += xpw[m * 128 + d] * v;
  }
#pragma unroll
  for (int m = 0; m < 12; ++m) red[wv][m][lane] = part[m];
  __syncthreads();
  for (int idx = t; idx < 12 * 64; idx += 256) {
    int m = idx >> 6, l = idx & 63;
    float s = red[0][m][l] + red[1][m][l] + red[2][m][l] + red[3][m][l];
    xdbl[((size_t)b * L_N + l0 + l) * 12 + m] = s;
  }
}

// ---------------------------------------------------------------------------
// K3: dt_proj + softplus + dA/dBx + associative scan (D_STATE=2) + y + z-gate.
// Block per (b,d); 36 tiles of 256 l; wave Kogge-Stone scan + cross-wave agg
// + block-serial carry.  Writes y in-place over xin (block owns the row).
// ---------------------------------------------------------------------------
__global__ __launch_bounds__(256) void k_scan(const float* __restrict__ xdbl,
                                              const float* __restrict__ dtw,
                                              const float* __restrict__ dtb,
                                              const float* __restrict__ alog,
                                              const float* __restrict__ dpar,
                                              const float* __restrict__ zbuf,
                                              float* __restrict__ xy) {
  __shared__ float agg[4][4];   // [wave][a0,x0,a1,x1]
  __shared__ float carry[2];
  int blk = blockIdx.x;
  int b = blk >> 7, d = blk & 127;
  int t = threadIdx.x;
  int lane = t & 63, w = t >> 6;
  float A0 = -__expf(alog[d * 2 + 0]);
  float A1 = -__expf(alog[d * 2 + 1]);
  float Dv = dpar[d];
  float dtbv = dtb[d];
  float w0 = dtw[d * 8 + 0], w1 = dtw[d * 8 + 1], w2 = dtw[d * 8 + 2], w3 = dtw[d * 8 + 3];
  float w4 = dtw[d * 8 + 4], w5 = dtw[d * 8 + 5], w6 = dtw[d * 8 + 6], w7 = dtw[d * 8 + 7];
  if (t == 0) { carry[0] = 0.f; carry[1] = 0.f; }
  __syncthreads();
  const float* xdb = xdbl + (size_t)b * L_N * 12;
  const float* zr = zbuf + ((size_t)(b * 128 + d)) * L_N;
  float* xr = xy + ((size_t)(b * 128 + d)) * L_N;
  for (int l0 = 0; l0 < L_N; l0 += 256) {
    int l = l0 + t;
    const float* xd = xdb + (size_t)l * 12;
    float4 q0 = *(const float4*)xd;
    float4 q1 = *(const float4*)(xd + 4);
    float4 q2 = *(const float4*)(xd + 8);   // B0,B1,C0,C1
    float xv = xr[l];
    float zv = zr[l];
    float dtpre = dtbv + w0 * q0.x + w1 * q0.y + w2 * q0.z + w3 * q0.w
                       + w4 * q1.x + w5 * q1.y + w6 * q1.z + w7 * q1.w;
    float dt = (dtpre > 15.f) ? dtpre : __logf(1.f + __expf(dtpre));  // softplus
    float a0 = __expf(dt * A0), a1 = __expf(dt * A1);
    float dtx = dt * xv;
    float x0 = dtx * q2.x, x1 = dtx * q2.y;
    // wave-level inclusive scan of (a, x) pairs, combine: (a1,b1)o(a2,b2)=(a1*a2, a2*b1+b2)
#pragma unroll
    for (int off = 1; off < 64; off <<= 1) {
      float pa0 = __shfl_up(a0, off, 64);
      float px0 = __shfl_up(x0, off, 64);
      float pa1 = __shfl_up(a1, off, 64);
      float px1 = __shfl_up(x1, off, 64);
      if (lane >= off) {
        x0 += a0 * px0; a0 *= pa0;
        x1 += a1 * px1; a1 *= pa1;
      }
    }
    if (lane == 63) { agg[w][0] = a0; agg[w][1] = x0; agg[w][2] = a1; agg[w][3] = x1; }
    __syncthreads();
    float h0 = carry[0], h1 = carry[1];
    for (int j = 0; j < w; ++j) {       // wave-uniform loop
      h0 = agg[j][0] * h0 + agg[j][1];
      h1 = agg[j][2] * h1 + agg[j][3];
    }
    h0 = a0 * h0 + x0;
    h1 = a1 * h1 + x1;
    float y = h0 * q2.z + h1 * q2.w + Dv * xv;
    y *= zv / (1.f + __expf(-zv));      // * SiLU(z)
    __syncthreads();
    if (t == 255) { carry[0] = h0; carry[1] = h1; }
    xr[l] = y;
  }
}

// ---------------------------------------------------------------------------
// K4: out_proj GEMM (128x128) + LayerNorm over channels + NCHW write.
// Block = (b, 64-l tile), reg tile 4l x 8o; LDS reduce for mean/var.
// ---------------------------------------------------------------------------
__global__ __launch_bounds__(256) void k_outln(const float* __restrict__ ybuf,
                                               const float* __restrict__ w2t,
                                               const float* __restrict__ gam,
                                               const float* __restrict__ bet,
                                               float* __restrict__ out) {
  __shared__ float ys[128][64];
  __shared__ float reds[64][17];
  __shared__ float redss[64][17];
  int blk = blockIdx.x;
  int b = blk / LT, lt = blk % LT;
  int l0 = lt * 64;
  int t = threadIdx.x;
#pragma unroll
  for (int i = 0; i < 32; ++i) {
    int idx = t + i * 256;
    int dd = idx >> 6, l = idx & 63;
    ys[dd][l] = ybuf[((size_t)(b * 128 + dd)) * L_N + l0 + l];
  }
  __syncthreads();
  int tl = t & 15, to = t >> 4;
  float acc[8][4];
#pragma unroll
  for (int j = 0; j < 8; ++j)
#pragma unroll
    for (int q = 0; q < 4; ++q) acc[j][q] = 0.f;
  const float* wbase = w2t + to * 8;
  for (int dd = 0; dd < 128; ++dd) {
    float4 yv = *(const float4*)&ys[dd][tl * 4];
    float yq[4] = {yv.x, yv.y, yv.z, yv.w};
    const float* wr = wbase + dd * 128;
    float4 wa = *(const float4*)wr;
    float4 wb = *(const float4*)(wr + 4);
    float wj[8] = {wa.x, wa.y, wa.z, wa.w, wb.x, wb.y, wb.z, wb.w};
#pragma unroll
    for (int j = 0; j < 8; ++j)
#pragma unroll
      for (int q = 0; q < 4; ++q) acc[j][q] += wj[j] * yq[q];
  }
#pragma unroll
  for (int q = 0; q < 4; ++q) {
    float s = 0.f, ss = 0.f;
#pragma unroll
    for (int j = 0; j < 8; ++j) { s += acc[j][q]; ss += acc[j][q] * acc[j][q]; }
    reds[tl * 4 + q][to] = s;
    redss[tl * 4 + q][to] = ss;
  }
  __syncthreads();
  float mu[4], rstd[4];
#pragma unroll
  for (int q = 0; q < 4; ++q) {
    float s = 0.f, ss = 0.f;
#pragma unroll
    for (int j = 0; j < 16; ++j) { s += reds[tl * 4 + q][j]; ss += redss[tl * 4 + q][j]; }
    float m = s * (1.f / 128.f);
    float v = ss * (1.f / 128.f) - m * m;
    mu[q] = m;
    rstd[q] = rsqrtf(v + 1e-5f);
  }
  size_t lbase = (size_t)l0 + tl * 4;
#pragma unroll
  for (int j = 0; j < 8; ++j) {
    int o = to * 8 + j;
    float g = gam[o], bb = bet[o];
    float4 v;
    v.x = (acc[j][0] - mu[0]) * rstd[0] * g + bb;
    v.y = (acc[j][1] - mu[1]) * rstd[1] * g + bb;
    v.z = (acc[j][2] - mu[2]) * rstd[2] * g + bb;
    v.w = (acc[j][3] - mu[3]) * rstd[3] * g + bb;
    *(float4*)(out + ((size_t)(b * 128 + o)) * L_N + lbase) = v;
  }
}

// ---------------------------------------------------------------------------
extern "C" void kernel_launch(void* const* d_in, const int* in_sizes, int n_in,
                              void* d_out, int out_size, void* d_ws, size_t ws_size,
                              hipStream_t stream) {
  const float* x    = (const float*)d_in[0];
  const float* w1   = (const float*)d_in[1];
  const float* cw   = (const float*)d_in[2];
  const float* cb   = (const float*)d_in[3];
  const float* xpw  = (const float*)d_in[4];
  const float* dtw  = (const float*)d_in[5];
  const float* dtb  = (const float*)d_in[6];
  const float* alog = (const float*)d_in[7];
  const float* dpar = (const float*)d_in[8];
  const float* w2   = (const float*)d_in[9];
  const float* gam  = (const float*)d_in[10];
  const float* bet  = (const float*)d_in[11];
  float* out = (float*)d_out;

  float* ws = (float*)d_ws;
  const size_t NBL = (size_t)B_N * C_N * L_N;     // 18,874,368
  float* xinpre = ws;                              // (B,D,L)
  float* zbuf   = xinpre + NBL;                    // (B,D,L)
  float* xiny   = zbuf + NBL;                      // (B,D,L): xin, then y in-place
  float* xdbl   = xiny + NBL;                      // (B,L,12)
  float* w1t    = xdbl + (size_t)B_N * L_N * 12;   // (128,256)
  float* w2t    = w1t + 256 * 128;                 // (128,128)

  k_wtrans<<<128, 256, 0, stream>>>(w1, w2, w1t, w2t);
  k_inproj<<<B_N * LT, 256, 0, stream>>>(x, w1t, xinpre, zbuf);
  k_conv_xproj<<<B_N * LT, 256, 0, stream>>>(xinpre, cw, cb, xpw, xiny, xdbl);
  k_scan<<<B_N * C_N, 256, 0, stream>>>(xdbl, dtw, dtb, alog, dpar, zbuf, xiny);
  k_outln<<<B_N * LT, 256, 0, stream>>>(xiny, w2t, gam, bet, out);
}

// Round 2
// 398.451 us; speedup vs baseline: 1.4342x; 1.4342x over previous
//
#include <hip/hip_runtime.h>
#include <hip/hip_bf16.h>

#define B_N 16
#define L_N 9216
#define LT64 144    // L_N / 64

typedef __attribute__((ext_vector_type(8))) short short8;
typedef __attribute__((ext_vector_type(4))) float floatx4;

// ---------------------------------------------------------------------------
// K0: weights fp32 -> bf16 (natural layouts already K-contiguous for A-op)
// ---------------------------------------------------------------------------
__global__ __launch_bounds__(256) void k_prep(const float* __restrict__ w1,
                                              const float* __restrict__ w2,
                                              __hip_bfloat16* __restrict__ w1bt,
                                              __hip_bfloat16* __restrict__ w2bt) {
  int i = blockIdx.x * 256 + threadIdx.x;
  if (i < 256 * 128) w1bt[i] = __float2bfloat16(w1[i]);
  if (i < 128 * 128) w2bt[i] = __float2bfloat16(w2[i]);
}

// ---------------------------------------------------------------------------
// K1: x (b,c=128,l) fp32 -> xt (b,l,c=128) bf16, LDS-tiled transpose
// ---------------------------------------------------------------------------
__global__ __launch_bounds__(256) void k_xt(const float* __restrict__ x,
                                            __hip_bfloat16* __restrict__ xt) {
  __shared__ float xs[128][65];
  int blk = blockIdx.x, b = blk / LT64, lt = blk % LT64, l0 = lt * 64;
  int t = threadIdx.x;
  const float* xb = x + (size_t)b * 128 * L_N;
#pragma unroll
  for (int i = 0; i < 8; ++i) {
    int idx = t + i * 256;              // 2048 float4: 128 c x 16 quads
    int c = idx >> 4, f4 = idx & 15;
    float4 v = *(const float4*)(xb + (size_t)c * L_N + l0 + f4 * 4);
    xs[c][f4 * 4 + 0] = v.x; xs[c][f4 * 4 + 1] = v.y;
    xs[c][f4 * 4 + 2] = v.z; xs[c][f4 * 4 + 3] = v.w;
  }
  __syncthreads();
  __hip_bfloat16* xtb = xt + ((size_t)b * L_N + l0) * 128;
#pragma unroll
  for (int i = 0; i < 16; ++i) {
    int idx = t + i * 256;              // 4096 pairs: 64 l x 64 c-pairs
    int cp = idx & 63, l = idx >> 6;
    __hip_bfloat162 u;
    u.x = __float2bfloat16(xs[2 * cp][l]);
    u.y = __float2bfloat16(xs[2 * cp + 1][l]);
    *(__hip_bfloat162*)(xtb + (size_t)l * 128 + 2 * cp) = u;
  }
}

// ---------------------------------------------------------------------------
// K2: in_proj via MFMA bf16.  Block tile M=256(e) x N=64(l), K=128(c).
// A = w1bt[e][c] frags from global; B = xt tile in LDS (xor-swizzled chunks).
// Wave wv owns e-strip [wv*64, wv*64+64).  D: row=e, col=l.
// ---------------------------------------------------------------------------
__global__ __launch_bounds__(256) void k_inproj(const __hip_bfloat16* __restrict__ xt,
                                                const __hip_bfloat16* __restrict__ w1bt,
                                                float* __restrict__ xinpre,
                                                float* __restrict__ zbuf) {
  __shared__ __hip_bfloat16 xs[64 * 128];
  int blk = blockIdx.x, b = blk / LT64, lt = blk % LT64, l0 = lt * 64;
  int t = threadIdx.x;
  const __hip_bfloat16* src = xt + ((size_t)b * L_N + l0) * 128;
#pragma unroll
  for (int i = 0; i < 4; ++i) {
    int idx = t + i * 256;              // 1024 16B chunks
    int row = idx >> 4, ch = idx & 15;
    uint4 v = *(const uint4*)(src + idx * 8);
    *(uint4*)&xs[row * 128 + ((ch ^ (row & 7)) * 8)] = v;
  }
  int lane = t & 63, wv = t >> 6;
  int col = lane & 15, quad = lane >> 4;
  int e0 = wv * 64;
  short8 afr[4][4];
  const __hip_bfloat16* wb = w1bt + (size_t)(e0 + col) * 128 + quad * 8;
#pragma unroll
  for (int mi = 0; mi < 4; ++mi)
#pragma unroll
    for (int ks = 0; ks < 4; ++ks)
      afr[mi][ks] = *(const short8*)(wb + mi * 16 * 128 + ks * 32);
  floatx4 vzero = {0.f, 0.f, 0.f, 0.f};
  floatx4 acc[4][4];
#pragma unroll
  for (int mi = 0; mi < 4; ++mi)
#pragma unroll
    for (int ni = 0; ni < 4; ++ni) acc[mi][ni] = vzero;
  __syncthreads();
#pragma unroll
  for (int ks = 0; ks < 4; ++ks) {
    short8 bfr[4];
#pragma unroll
    for (int ni = 0; ni < 4; ++ni) {
      int row = ni * 16 + col;
      bfr[ni] = *(const short8*)&xs[row * 128 + (((ks * 4 + quad) ^ (row & 7)) * 8)];
    }
#pragma unroll
    for (int mi = 0; mi < 4; ++mi)
#pragma unroll
      for (int ni = 0; ni < 4; ++ni)
        acc[mi][ni] = __builtin_amdgcn_mfma_f32_16x16x32_bf16(afr[mi][ks], bfr[ni], acc[mi][ni], 0, 0, 0);
  }
  float* base = (e0 < 128) ? (xinpre + ((size_t)b * 128 + e0) * L_N)
                           : (zbuf + ((size_t)b * 128 + (e0 - 128)) * L_N);
#pragma unroll
  for (int mi = 0; mi < 4; ++mi)
#pragma unroll
    for (int r = 0; r < 4; ++r) {
      int erow = mi * 16 + quad * 4 + r;
      float* dst = base + (size_t)erow * L_N + l0 + col;
#pragma unroll
      for (int ni = 0; ni < 4; ++ni) dst[ni * 16] = acc[mi][ni][r];
    }
}

// ---------------------------------------------------------------------------
// K3: depthwise causal conv (k=4) + SiLU + x_proj (12x128).  (unchanged, fp32)
// ---------------------------------------------------------------------------
__global__ __launch_bounds__(256) void k_conv_xproj(const float* __restrict__ xinpre,
                                                    const float* __restrict__ cw,
                                                    const float* __restrict__ cb,
                                                    const float* __restrict__ xpw,
                                                    float* __restrict__ xin,
                                                    float* __restrict__ xdbl) {
  __shared__ float xs[128][68];
  __shared__ float red[4][12][64];
  int blk = blockIdx.x, b = blk / LT64, lt = blk % LT64, l0 = lt * 64;
  int t = threadIdx.x;
  for (int idx = t; idx < 128 * 67; idx += 256) {
    int dd = idx / 67, j = idx % 67;
    int l = l0 - 3 + j;
    xs[dd][j] = (l >= 0) ? xinpre[((size_t)(b * 128 + dd)) * L_N + l] : 0.f;
  }
  __syncthreads();
  int lane = t & 63, wv = t >> 6;
  float part[12];
#pragma unroll
  for (int m = 0; m < 12; ++m) part[m] = 0.f;
  for (int dd = 0; dd < 32; ++dd) {
    int d = wv * 32 + dd;
    float v = cb[d] + cw[d * 4 + 0] * xs[d][lane] + cw[d * 4 + 1] * xs[d][lane + 1]
                    + cw[d * 4 + 2] * xs[d][lane + 2] + cw[d * 4 + 3] * xs[d][lane + 3];
    v = v / (1.f + __expf(-v));                    // SiLU
    xin[((size_t)(b * 128 + d)) * L_N + l0 + lane] = v;
#pragma unroll
    for (int m = 0; m < 12; ++m) part[m] += xpw[m * 128 + d] * v;
  }
#pragma unroll
  for (int m = 0; m < 12; ++m) red[wv][m][lane] = part[m];
  __syncthreads();
  for (int idx = t; idx < 12 * 64; idx += 256) {
    int m = idx >> 6, l = idx & 63;
    float s = red[0][m][l] + red[1][m][l] + red[2][m][l] + red[3][m][l];
    xdbl[((size_t)b * L_N + l0 + l) * 12 + m] = s;
  }
}

// ---------------------------------------------------------------------------
// K4: dt_proj + softplus + scan (D_STATE=2) + y + z-gate.  Reads xin/z,
// writes y to a separate buffer (xinpre is dead after conv, reused as y).
// ---------------------------------------------------------------------------
__global__ __launch_bounds__(256) void k_scan(const float* __restrict__ xdbl,
                                              const float* __restrict__ dtw,
                                              const float* __restrict__ dtb,
                                              const float* __restrict__ alog,
                                              const float* __restrict__ dpar,
                                              const float* __restrict__ xin,
                                              const float* __restrict__ zbuf,
                                              float* __restrict__ yb) {
  __shared__ float agg[4][4];
  __shared__ float carry[2];
  int blk = blockIdx.x;
  int b = blk >> 7, d = blk & 127;
  int t = threadIdx.x;
  int lane = t & 63, w = t >> 6;
  float A0 = -__expf(alog[d * 2 + 0]);
  float A1 = -__expf(alog[d * 2 + 1]);
  float Dv = dpar[d];
  float dtbv = dtb[d];
  float w0 = dtw[d * 8 + 0], w1 = dtw[d * 8 + 1], w2 = dtw[d * 8 + 2], w3 = dtw[d * 8 + 3];
  float w4 = dtw[d * 8 + 4], w5 = dtw[d * 8 + 5], w6 = dtw[d * 8 + 6], w7 = dtw[d * 8 + 7];
  if (t == 0) { carry[0] = 0.f; carry[1] = 0.f; }
  __syncthreads();
  const float* xdb = xdbl + (size_t)b * L_N * 12;
  const float* xi = xin + ((size_t)(b * 128 + d)) * L_N;
  const float* zr = zbuf + ((size_t)(b * 128 + d)) * L_N;
  float* yo = yb + ((size_t)(b * 128 + d)) * L_N;
  for (int l0 = 0; l0 < L_N; l0 += 256) {
    int l = l0 + t;
    const float* xd = xdb + (size_t)l * 12;
    float4 q0 = *(const float4*)xd;
    float4 q1 = *(const float4*)(xd + 4);
    float4 q2 = *(const float4*)(xd + 8);   // B0,B1,C0,C1
    float xv = xi[l];
    float zv = zr[l];
    float dtpre = dtbv + w0 * q0.x + w1 * q0.y + w2 * q0.z + w3 * q0.w
                       + w4 * q1.x + w5 * q1.y + w6 * q1.z + w7 * q1.w;
    float dt = (dtpre > 15.f) ? dtpre : __logf(1.f + __expf(dtpre));
    float a0 = __expf(dt * A0), a1 = __expf(dt * A1);
    float dtx = dt * xv;
    float x0 = dtx * q2.x, x1 = dtx * q2.y;
#pragma unroll
    for (int off = 1; off < 64; off <<= 1) {
      float pa0 = __shfl_up(a0, off, 64);
      float px0 = __shfl_up(x0, off, 64);
      float pa1 = __shfl_up(a1, off, 64);
      float px1 = __shfl_up(x1, off, 64);
      if (lane >= off) {
        x0 += a0 * px0; a0 *= pa0;
        x1 += a1 * px1; a1 *= pa1;
      }
    }
    if (lane == 63) { agg[w][0] = a0; agg[w][1] = x0; agg[w][2] = a1; agg[w][3] = x1; }
    __syncthreads();
    float h0 = carry[0], h1 = carry[1];
    for (int j = 0; j < w; ++j) {
      h0 = agg[j][0] * h0 + agg[j][1];
      h1 = agg[j][2] * h1 + agg[j][3];
    }
    h0 = a0 * h0 + x0;
    h1 = a1 * h1 + x1;
    float y = h0 * q2.z + h1 * q2.w + Dv * xv;
    y *= zv / (1.f + __expf(-zv));
    __syncthreads();
    if (t == 255) { carry[0] = h0; carry[1] = h1; }
    yo[l] = y;
  }
}

// ---------------------------------------------------------------------------
// K5: y (b,d=128,l) fp32 -> yt (b,l,d=128) bf16 transpose
// ---------------------------------------------------------------------------
__global__ __launch_bounds__(256) void k_yt(const float* __restrict__ y,
                                            __hip_bfloat16* __restrict__ yt) {
  __shared__ float ys[128][65];
  int blk = blockIdx.x, b = blk / LT64, lt = blk % LT64, l0 = lt * 64;
  int t = threadIdx.x;
#pragma unroll
  for (int i = 0; i < 32; ++i) {
    int idx = t + i * 256;
    int d = idx >> 6, l = idx & 63;
    ys[d][l] = y[((size_t)(b * 128 + d)) * L_N + l0 + l];
  }
  __syncthreads();
  __hip_bfloat16* ytb = yt + ((size_t)b * L_N + l0) * 128;
#pragma unroll
  for (int i = 0; i < 16; ++i) {
    int idx = t + i * 256;
    int dp = idx & 63, l = idx >> 6;
    __hip_bfloat162 u;
    u.x = __float2bfloat16(ys[2 * dp][l]);
    u.y = __float2bfloat16(ys[2 * dp + 1][l]);
    *(__hip_bfloat162*)(ytb + (size_t)l * 128 + 2 * dp) = u;
  }
}

// ---------------------------------------------------------------------------
// K6: out_proj via MFMA (M=128 o, N=64 l, K=128 d) + LayerNorm + NCHW write.
// Wave wv owns o-strip [wv*32, wv*32+32), all 64 l.  LN: in-lane sum ->
// shfl_xor over quads -> LDS cross-wave reduce.
// ---------------------------------------------------------------------------
__global__ __launch_bounds__(256) void k_outln(const __hip_bfloat16* __restrict__ yt,
                                               const __hip_bfloat16* __restrict__ w2bt,
                                               const float* __restrict__ gam,
                                               const float* __restrict__ bet,
                                               float* __restrict__ out) {
  __shared__ __hip_bfloat16 ws2[128 * 128];
  __shared__ __hip_bfloat16 yts[64 * 128];
  __shared__ float gs[128], bs[128];
  __shared__ float red_s[4][64], red_q[4][64];
  int blk = blockIdx.x, b = blk / LT64, lt = blk % LT64, l0 = lt * 64;
  int t = threadIdx.x;
  if (t < 128) { gs[t] = gam[t]; bs[t] = bet[t]; }
#pragma unroll
  for (int i = 0; i < 8; ++i) {
    int idx = t + i * 256;              // 2048 chunks of w2
    int row = idx >> 4, ch = idx & 15;
    uint4 v = *(const uint4*)(w2bt + idx * 8);
    *(uint4*)&ws2[row * 128 + ((ch ^ (row & 7)) * 8)] = v;
  }
  const __hip_bfloat16* src = yt + ((size_t)b * L_N + l0) * 128;
#pragma unroll
  for (int i = 0; i < 4; ++i) {
    int idx = t + i * 256;              // 1024 chunks of yt tile
    int row = idx >> 4, ch = idx & 15;
    uint4 v = *(const uint4*)(src + idx * 8);
    *(uint4*)&yts[row * 128 + ((ch ^ (row & 7)) * 8)] = v;
  }
  __syncthreads();
  int lane = t & 63, wv = t >> 6;
  int col = lane & 15, quad = lane >> 4;
  int o0 = wv * 32;
  short8 afr[2][4];
#pragma unroll
  for (int mi = 0; mi < 2; ++mi)
#pragma unroll
    for (int ks = 0; ks < 4; ++ks) {
      int row = o0 + mi * 16 + col;
      afr[mi][ks] = *(const short8*)&ws2[row * 128 + (((ks * 4 + quad) ^ (row & 7)) * 8)];
    }
  floatx4 vzero = {0.f, 0.f, 0.f, 0.f};
  floatx4 acc[2][4];
#pragma unroll
  for (int mi = 0; mi < 2; ++mi)
#pragma unroll
    for (int ni = 0; ni < 4; ++ni) acc[mi][ni] = vzero;
#pragma unroll
  for (int ks = 0; ks < 4; ++ks) {
    short8 bfr[4];
#pragma unroll
    for (int ni = 0; ni < 4; ++ni) {
      int row = ni * 16 + col;
      bfr[ni] = *(const short8*)&yts[row * 128 + (((ks * 4 + quad) ^ (row & 7)) * 8)];
    }
#pragma unroll
    for (int mi = 0; mi < 2; ++mi)
#pragma unroll
      for (int ni = 0; ni < 4; ++ni)
        acc[mi][ni] = __builtin_amdgcn_mfma_f32_16x16x32_bf16(afr[mi][ks], bfr[ni], acc[mi][ni], 0, 0, 0);
  }
  // LN reduction: each lane sums its 8 o-values per ni (o-strip partial)
  float s[4], q[4];
#pragma unroll
  for (int ni = 0; ni < 4; ++ni) {
    float ss = 0.f, qq = 0.f;
#pragma unroll
    for (int mi = 0; mi < 2; ++mi)
#pragma unroll
      for (int r = 0; r < 4; ++r) {
        float v = acc[mi][ni][r];
        ss += v; qq += v * v;
      }
    ss += __shfl_xor(ss, 16, 64); ss += __shfl_xor(ss, 32, 64);
    qq += __shfl_xor(qq, 16, 64); qq += __shfl_xor(qq, 32, 64);
    s[ni] = ss; q[ni] = qq;
  }
  if (quad == 0) {
#pragma unroll
    for (int ni = 0; ni < 4; ++ni) {
      red_s[wv][ni * 16 + col] = s[ni];
      red_q[wv][ni * 16 + col] = q[ni];
    }
  }
  __syncthreads();
  float mu[4], rstd[4];
#pragma unroll
  for (int ni = 0; ni < 4; ++ni) {
    int li = ni * 16 + col;
    float ts = red_s[0][li] + red_s[1][li] + red_s[2][li] + red_s[3][li];
    float tq = red_q[0][li] + red_q[1][li] + red_q[2][li] + red_q[3][li];
    float m = ts * (1.f / 128.f);
    float var = tq * (1.f / 128.f) - m * m;
    mu[ni] = m;
    rstd[ni] = rsqrtf(var + 1e-5f);
  }
  float* ob = out + (size_t)b * 128 * L_N;
#pragma unroll
  for (int mi = 0; mi < 2; ++mi)
#pragma unroll
    for (int r = 0; r < 4; ++r) {
      int o = o0 + mi * 16 + quad * 4 + r;
      float g = gs[o], bb = bs[o];
#pragma unroll
      for (int ni = 0; ni < 4; ++ni)
        ob[(size_t)o * L_N + l0 + ni * 16 + col] = (acc[mi][ni][r] - mu[ni]) * rstd[ni] * g + bb;
    }
}

// ---------------------------------------------------------------------------
extern "C" void kernel_launch(void* const* d_in, const int* in_sizes, int n_in,
                              void* d_out, int out_size, void* d_ws, size_t ws_size,
                              hipStream_t stream) {
  const float* x    = (const float*)d_in[0];
  const float* w1   = (const float*)d_in[1];
  const float* cw   = (const float*)d_in[2];
  const float* cb   = (const float*)d_in[3];
  const float* xpw  = (const float*)d_in[4];
  const float* dtw  = (const float*)d_in[5];
  const float* dtb  = (const float*)d_in[6];
  const float* alog = (const float*)d_in[7];
  const float* dpar = (const float*)d_in[8];
  const float* w2   = (const float*)d_in[9];
  const float* gam  = (const float*)d_in[10];
  const float* bet  = (const float*)d_in[11];
  float* out = (float*)d_out;

  float* ws = (float*)d_ws;
  const size_t NBL = (size_t)B_N * 128 * L_N;      // 18,874,368
  float* xinpre = ws;                               // fp32 (B,D,L); later y
  float* zbuf   = ws + NBL;                         // fp32
  float* xin    = ws + 2 * NBL;                     // fp32
  float* xdbl   = ws + 3 * NBL;                     // fp32 (B,L,12)
  __hip_bfloat16* xt = (__hip_bfloat16*)(xdbl + (size_t)B_N * L_N * 12);  // bf16 (B,L,128); later yt
  __hip_bfloat16* w1bt = xt + NBL;
  __hip_bfloat16* w2bt = w1bt + 256 * 128;

  k_prep<<<128, 256, 0, stream>>>(w1, w2, w1bt, w2bt);
  k_xt<<<B_N * LT64, 256, 0, stream>>>(x, xt);
  k_inproj<<<B_N * LT64, 256, 0, stream>>>(xt, w1bt, xinpre, zbuf);
  k_conv_xproj<<<B_N * LT64, 256, 0, stream>>>(xinpre, cw, cb, xpw, xin, xdbl);
  k_scan<<<B_N * 128, 256, 0, stream>>>(xdbl, dtw, dtb, alog, dpar, xin, zbuf, xinpre);
  k_yt<<<B_N * LT64, 256, 0, stream>>>(xinpre, xt);
  k_outln<<<B_N * LT64, 256, 0, stream>>>(xt, w2bt, gam, bet, out);
}

// Round 3
// 316.031 us; speedup vs baseline: 1.8083x; 1.2608x over previous
//
#include <hip/hip_runtime.h>
#include <hip/hip_bf16.h>

#define B_N 16
#define L_N 9216
#define LT64 144    // L_N / 64

typedef __attribute__((ext_vector_type(8))) short short8;
typedef __attribute__((ext_vector_type(4))) float floatx4;

__device__ __forceinline__ float bfu(unsigned short u) {
  return __uint_as_float(((unsigned int)u) << 16);
}
__device__ __forceinline__ unsigned short fbf(float f) {
  __hip_bfloat16 h = __float2bfloat16(f);
  return *(unsigned short*)&h;
}

// ---------------------------------------------------------------------------
// K0: weights fp32 -> bf16
// ---------------------------------------------------------------------------
__global__ __launch_bounds__(256) void k_prep(const float* __restrict__ w1,
                                              const float* __restrict__ w2,
                                              __hip_bfloat16* __restrict__ w1bt,
                                              __hip_bfloat16* __restrict__ w2bt) {
  int i = blockIdx.x * 256 + threadIdx.x;
  if (i < 256 * 128) w1bt[i] = __float2bfloat16(w1[i]);
  if (i < 128 * 128) w2bt[i] = __float2bfloat16(w2[i]);
}

// ---------------------------------------------------------------------------
// K1: x (b,c=128,l) fp32 -> xt (b,l,c=128) bf16, LDS-tiled transpose
// ---------------------------------------------------------------------------
__global__ __launch_bounds__(256) void k_xt(const float* __restrict__ x,
                                            __hip_bfloat16* __restrict__ xt) {
  __shared__ float xs[128][65];
  int blk = blockIdx.x, b = blk / LT64, lt = blk % LT64, l0 = lt * 64;
  int t = threadIdx.x;
  const float* xb = x + (size_t)b * 128 * L_N;
#pragma unroll
  for (int i = 0; i < 8; ++i) {
    int idx = t + i * 256;
    int c = idx >> 4, f4 = idx & 15;
    float4 v = *(const float4*)(xb + (size_t)c * L_N + l0 + f4 * 4);
    xs[c][f4 * 4 + 0] = v.x; xs[c][f4 * 4 + 1] = v.y;
    xs[c][f4 * 4 + 2] = v.z; xs[c][f4 * 4 + 3] = v.w;
  }
  __syncthreads();
  __hip_bfloat16* xtb = xt + ((size_t)b * L_N + l0) * 128;
#pragma unroll
  for (int i = 0; i < 16; ++i) {
    int idx = t + i * 256;
    int cp = idx & 63, l = idx >> 6;
    __hip_bfloat162 u;
    u.x = __float2bfloat16(xs[2 * cp][l]);
    u.y = __float2bfloat16(xs[2 * cp + 1][l]);
    *(__hip_bfloat162*)(xtb + (size_t)l * 128 + 2 * cp) = u;
  }
}

// ---------------------------------------------------------------------------
// K2: in_proj MFMA (M=256e x N=64l x K=128c) fused with depthwise conv(k=4)
// + SiLU + x_proj.  Waves 0,1 (e<128): acc -> LDS conv buffer; waves 2,3:
// z -> global bf16.  Left boundary (3 cols) recomputed via VALU dots.
// Outputs: zb bf16 (b,d,l), xinb bf16 (b,d,l), xdblT fp32 (b,12,L).
// ---------------------------------------------------------------------------
__global__ __launch_bounds__(256) void k_inproj_conv(
    const __hip_bfloat16* __restrict__ xt, const __hip_bfloat16* __restrict__ w1bt,
    const float* __restrict__ cw, const float* __restrict__ cb,
    const float* __restrict__ xpw,
    __hip_bfloat16* __restrict__ xinb, __hip_bfloat16* __restrict__ zb,
    float* __restrict__ xdblT) {
  __shared__ __align__(16) char smem[16384];     // xs (16KB) then red (12KB)
  __hip_bfloat16* xs = (__hip_bfloat16*)smem;    // swizzled B tile [64][128]
  float (*red)[12][64] = (float(*)[12][64])smem; // [4][12][64] xproj partials
  __shared__ float cvs[128][68];                 // conv staging [d][3+64+1]
  int blk = blockIdx.x, b = blk / LT64, lt = blk % LT64, l0 = lt * 64;
  int t = threadIdx.x;
  const __hip_bfloat16* src = xt + ((size_t)b * L_N + l0) * 128;
#pragma unroll
  for (int i = 0; i < 4; ++i) {
    int idx = t + i * 256;              // 1024 16B chunks
    int row = idx >> 4, ch = idx & 15;
    uint4 v = *(const uint4*)(src + idx * 8);
    *(uint4*)&xs[row * 128 + ((ch ^ (row & 7)) * 8)] = v;
  }
  int lane = t & 63, wv = t >> 6;
  int col = lane & 15, quad = lane >> 4;
  int e0 = wv * 64;
  short8 afr[4][4];
  const __hip_bfloat16* wb = w1bt + (size_t)(e0 + col) * 128 + quad * 8;
#pragma unroll
  for (int mi = 0; mi < 4; ++mi)
#pragma unroll
    for (int ks = 0; ks < 4; ++ks)
      afr[mi][ks] = *(const short8*)(wb + mi * 16 * 128 + ks * 32);
  floatx4 vzero = {0.f, 0.f, 0.f, 0.f};
  floatx4 acc[4][4];
#pragma unroll
  for (int mi = 0; mi < 4; ++mi)
#pragma unroll
    for (int ni = 0; ni < 4; ++ni) acc[mi][ni] = vzero;
  __syncthreads();                               // B1
#pragma unroll
  for (int ks = 0; ks < 4; ++ks) {
    short8 bfr[4];
#pragma unroll
    for (int ni = 0; ni < 4; ++ni) {
      int row = ni * 16 + col;
      bfr[ni] = *(const short8*)&xs[row * 128 + (((ks * 4 + quad) ^ (row & 7)) * 8)];
    }
#pragma unroll
    for (int mi = 0; mi < 4; ++mi)
#pragma unroll
      for (int ni = 0; ni < 4; ++ni)
        acc[mi][ni] = __builtin_amdgcn_mfma_f32_16x16x32_bf16(afr[mi][ks], bfr[ni], acc[mi][ni], 0, 0, 0);
  }
  // left-boundary xinpre (3 columns, d = t < 128) via VALU dots
  if (t < 128) {
    float s0 = 0.f, s1 = 0.f, s2 = 0.f;
    if (lt > 0) {
      const __hip_bfloat16* wr = w1bt + (size_t)t * 128;
      const __hip_bfloat16* x0r = xt + ((size_t)b * L_N + l0 - 3) * 128;
#pragma unroll
      for (int c8 = 0; c8 < 16; ++c8) {
        short8 wc = *(const short8*)(wr + c8 * 8);
        short8 xa = *(const short8*)(x0r + c8 * 8);
        short8 xb2 = *(const short8*)(x0r + 128 + c8 * 8);
        short8 xc = *(const short8*)(x0r + 256 + c8 * 8);
#pragma unroll
        for (int e = 0; e < 8; ++e) {
          float wf = bfu((unsigned short)wc[e]);
          s0 += wf * bfu((unsigned short)xa[e]);
          s1 += wf * bfu((unsigned short)xb2[e]);
          s2 += wf * bfu((unsigned short)xc[e]);
        }
      }
    }
    cvs[t][0] = s0; cvs[t][1] = s1; cvs[t][2] = s2;
  }
  // epilogue: d-half -> cvs, z-half -> global bf16
  if (wv < 2) {
#pragma unroll
    for (int mi = 0; mi < 4; ++mi)
#pragma unroll
      for (int r = 0; r < 4; ++r) {
        int d = e0 + mi * 16 + quad * 4 + r;
#pragma unroll
        for (int ni = 0; ni < 4; ++ni) cvs[d][3 + ni * 16 + col] = acc[mi][ni][r];
      }
  } else {
    __hip_bfloat16* zbase = zb + ((size_t)b * 128 + (e0 - 128)) * L_N + l0;
#pragma unroll
    for (int mi = 0; mi < 4; ++mi)
#pragma unroll
      for (int r = 0; r < 4; ++r) {
        int dr = mi * 16 + quad * 4 + r;
#pragma unroll
        for (int ni = 0; ni < 4; ++ni)
          zbase[(size_t)dr * L_N + ni * 16 + col] = __float2bfloat16(acc[mi][ni][r]);
      }
  }
  __syncthreads();                               // B2 (xs dead, cvs ready)
  // conv + SiLU + x_proj partials; wave wv owns d in [wv*32, wv*32+32)
  float part[12];
#pragma unroll
  for (int m = 0; m < 12; ++m) part[m] = 0.f;
  for (int dd = 0; dd < 32; ++dd) {
    int d = wv * 32 + dd;
    float v = cb[d] + cw[d * 4 + 0] * cvs[d][lane] + cw[d * 4 + 1] * cvs[d][lane + 1]
                    + cw[d * 4 + 2] * cvs[d][lane + 2] + cw[d * 4 + 3] * cvs[d][lane + 3];
    v = v / (1.f + __expf(-v));                  // SiLU
    xinb[((size_t)b * 128 + d) * L_N + l0 + lane] = __float2bfloat16(v);
#pragma unroll
    for (int m = 0; m < 12; ++m) part[m] += xpw[m * 128 + d] * v;
  }
#pragma unroll
  for (int m = 0; m < 12; ++m) red[wv][m][lane] = part[m];
  __syncthreads();                               // B3
  for (int idx = t; idx < 12 * 64; idx += 256) {
    int m = idx >> 6, l = idx & 63;
    float s = red[0][m][l] + red[1][m][l] + red[2][m][l] + red[3][m][l];
    xdblT[((size_t)b * 12 + m) * L_N + l0 + l] = s;
  }
}

// ---------------------------------------------------------------------------
// K3: dt_proj + softplus + scan (D_STATE=2) + y + z-gate.
// Block per (b,d); 9 tiles of 1024 l; 4 elems/lane serial scan + wave KS on
// lane aggregates + cross-wave LDS agg + block-serial carry.
// ---------------------------------------------------------------------------
__global__ __launch_bounds__(256) void k_scan(
    const float* __restrict__ xdblT, const float* __restrict__ dtw,
    const float* __restrict__ dtb, const float* __restrict__ alog,
    const float* __restrict__ dpar,
    const __hip_bfloat16* __restrict__ xinb, const __hip_bfloat16* __restrict__ zb,
    __hip_bfloat16* __restrict__ yb) {
  __shared__ float agg[4][4];
  __shared__ float carry[2];
  int blk = blockIdx.x, b = blk >> 7, d = blk & 127;
  int t = threadIdx.x, lane = t & 63, wv = t >> 6;
  float A0 = -__expf(alog[2 * d]), A1 = -__expf(alog[2 * d + 1]);
  float Dv = dpar[d], dtbv = dtb[d];
  float w[8];
#pragma unroll
  for (int i = 0; i < 8; ++i) w[i] = dtw[d * 8 + i];
  if (t == 0) { carry[0] = 0.f; carry[1] = 0.f; }
  __syncthreads();
  const float* xdT = xdblT + (size_t)b * 12 * L_N;
  const unsigned short* xi = (const unsigned short*)xinb + ((size_t)b * 128 + d) * L_N;
  const unsigned short* zr = (const unsigned short*)zb + ((size_t)b * 128 + d) * L_N;
  unsigned short* yo = (unsigned short*)yb + ((size_t)b * 128 + d) * L_N;
  for (int it = 0; it < 9; ++it) {
    int lb = it * 1024 + t * 4;
    float4 q[12];
#pragma unroll
    for (int m = 0; m < 12; ++m) q[m] = *(const float4*)(xdT + (size_t)m * L_N + lb);
    ushort4 xu = *(const ushort4*)(xi + lb);
    ushort4 zu = *(const ushort4*)(zr + lb);
    float xv[4] = {bfu(xu.x), bfu(xu.y), bfu(xu.z), bfu(xu.w)};
    float zv[4] = {bfu(zu.x), bfu(zu.y), bfu(zu.z), bfu(zu.w)};
    float A0p[4], X0p[4], A1p[4], X1p[4];
#pragma unroll
    for (int j = 0; j < 4; ++j) {
      float dtp = dtbv;
#pragma unroll
      for (int m = 0; m < 8; ++m) dtp += w[m] * ((const float*)&q[m])[j];
      float dt = (dtp > 15.f) ? dtp : __logf(1.f + __expf(dtp));  // softplus
      float a0 = __expf(dt * A0), a1 = __expf(dt * A1);
      float dtx = dt * xv[j];
      float x0 = dtx * ((const float*)&q[8])[j];
      float x1 = dtx * ((const float*)&q[9])[j];
      if (j == 0) { A0p[0] = a0; X0p[0] = x0; A1p[0] = a1; X1p[0] = x1; }
      else {
        A0p[j] = a0 * A0p[j - 1]; X0p[j] = a0 * X0p[j - 1] + x0;
        A1p[j] = a1 * A1p[j - 1]; X1p[j] = a1 * X1p[j - 1] + x1;
      }
    }
    float wA0 = A0p[3], wX0 = X0p[3], wA1 = A1p[3], wX1 = X1p[3];
#pragma unroll
    for (int off = 1; off < 64; off <<= 1) {
      float pA0 = __shfl_up(wA0, off, 64), pX0 = __shfl_up(wX0, off, 64);
      float pA1 = __shfl_up(wA1, off, 64), pX1 = __shfl_up(wX1, off, 64);
      if (lane >= off) {
        wX0 += wA0 * pX0; wA0 *= pA0;
        wX1 += wA1 * pX1; wA1 *= pA1;
      }
    }
    if (lane == 63) { agg[wv][0] = wA0; agg[wv][1] = wX0; agg[wv][2] = wA1; agg[wv][3] = wX1; }
    float eA0 = __shfl_up(wA0, 1, 64), eX0 = __shfl_up(wX0, 1, 64);
    float eA1 = __shfl_up(wA1, 1, 64), eX1 = __shfl_up(wX1, 1, 64);
    if (lane == 0) { eA0 = 1.f; eX0 = 0.f; eA1 = 1.f; eX1 = 0.f; }
    __syncthreads();
    float h0 = carry[0], h1 = carry[1];
    for (int jw = 0; jw < wv; ++jw) {            // wave-uniform
      h0 = agg[jw][0] * h0 + agg[jw][1];
      h1 = agg[jw][2] * h1 + agg[jw][3];
    }
    h0 = eA0 * h0 + eX0;                         // lane input state
    h1 = eA1 * h1 + eX1;
    __syncthreads();
    if (t == 255) { carry[0] = A0p[3] * h0 + X0p[3]; carry[1] = A1p[3] * h1 + X1p[3]; }
    ushort4 yu;
    unsigned short* yp = (unsigned short*)&yu;
#pragma unroll
    for (int j = 0; j < 4; ++j) {
      float hh0 = A0p[j] * h0 + X0p[j];
      float hh1 = A1p[j] * h1 + X1p[j];
      float y = hh0 * ((const float*)&q[10])[j] + hh1 * ((const float*)&q[11])[j] + Dv * xv[j];
      y *= zv[j] / (1.f + __expf(-zv[j]));
      yp[j] = fbf(y);
    }
    *(ushort4*)(yo + lb) = yu;
  }
}

// ---------------------------------------------------------------------------
// K4: out_proj MFMA (M=128o x N=64l x K=128d) + LayerNorm + NCHW write.
// y bf16 (b,d,l) staged [d][l] in LDS, gather-packed into swizzled [l][d]
// MFMA-B tile.  w2 A-fragments direct from global (L2-hot).
// ---------------------------------------------------------------------------
__global__ __launch_bounds__(256) void k_outln(
    const __hip_bfloat16* __restrict__ yb, const __hip_bfloat16* __restrict__ w2bt,
    const float* __restrict__ gam, const float* __restrict__ bet,
    float* __restrict__ out) {
  __shared__ unsigned short st[128][68];
  __shared__ __hip_bfloat16 yts[64 * 128];
  __shared__ float red_s[4][64], red_q[4][64];
  __shared__ float gs[128], bs[128];
  int blk = blockIdx.x, b = blk / LT64, lt = blk % LT64, l0 = lt * 64;
  int t = threadIdx.x;
  if (t < 128) { gs[t] = gam[t]; bs[t] = bet[t]; }
  const unsigned short* ybb = (const unsigned short*)yb + (size_t)b * 128 * L_N + l0;
#pragma unroll
  for (int i = 0; i < 8; ++i) {
    int idx = t + i * 256;              // 2048 ushort4 loads (128d x 16 l-quads)
    int dd = idx >> 4, l4 = (idx & 15) * 4;
    ushort4 v = *(const ushort4*)(ybb + (size_t)dd * L_N + l4);
    *(ushort4*)&st[dd][l4] = v;
  }
  __syncthreads();
#pragma unroll
  for (int p = 0; p < 4; ++p) {
    int gi = t + p * 256;               // 1024 chunk-packs (64 l x 16 ch)
    int l = gi & 63, ch = gi >> 6;
    short8 c;
#pragma unroll
    for (int j = 0; j < 8; ++j) c[j] = (short)st[ch * 8 + j][l];
    *(short8*)&yts[l * 128 + ((ch ^ (l & 7)) * 8)] = c;
  }
  int lane = t & 63, wv = t >> 6;
  int col = lane & 15, quad = lane >> 4;
  int o0 = wv * 32;
  short8 afr[2][4];
#pragma unroll
  for (int mi = 0; mi < 2; ++mi)
#pragma unroll
    for (int ks = 0; ks < 4; ++ks)
      afr[mi][ks] = *(const short8*)(w2bt + (size_t)(o0 + mi * 16 + col) * 128 + ks * 32 + quad * 8);
  floatx4 vzero = {0.f, 0.f, 0.f, 0.f};
  floatx4 acc[2][4];
#pragma unroll
  for (int mi = 0; mi < 2; ++mi)
#pragma unroll
    for (int ni = 0; ni < 4; ++ni) acc[mi][ni] = vzero;
  __syncthreads();
#pragma unroll
  for (int ks = 0; ks < 4; ++ks) {
    short8 bfr[4];
#pragma unroll
    for (int ni = 0; ni < 4; ++ni) {
      int row = ni * 16 + col;
      bfr[ni] = *(const short8*)&yts[row * 128 + (((ks * 4 + quad) ^ (row & 7)) * 8)];
    }
#pragma unroll
    for (int mi = 0; mi < 2; ++mi)
#pragma unroll
      for (int ni = 0; ni < 4; ++ni)
        acc[mi][ni] = __builtin_amdgcn_mfma_f32_16x16x32_bf16(afr[mi][ks], bfr[ni], acc[mi][ni], 0, 0, 0);
  }
  float s[4], q[4];
#pragma unroll
  for (int ni = 0; ni < 4; ++ni) {
    float ss = 0.f, qq = 0.f;
#pragma unroll
    for (int mi = 0; mi < 2; ++mi)
#pragma unroll
      for (int r = 0; r < 4; ++r) {
        float v = acc[mi][ni][r];
        ss += v; qq += v * v;
      }
    ss += __shfl_xor(ss, 16, 64); ss += __shfl_xor(ss, 32, 64);
    qq += __shfl_xor(qq, 16, 64); qq += __shfl_xor(qq, 32, 64);
    s[ni] = ss; q[ni] = qq;
  }
  if (quad == 0) {
#pragma unroll
    for (int ni = 0; ni < 4; ++ni) {
      red_s[wv][ni * 16 + col] = s[ni];
      red_q[wv][ni * 16 + col] = q[ni];
    }
  }
  __syncthreads();
  float mu[4], rstd[4];
#pragma unroll
  for (int ni = 0; ni < 4; ++ni) {
    int li = ni * 16 + col;
    float ts = red_s[0][li] + red_s[1][li] + red_s[2][li] + red_s[3][li];
    float tq = red_q[0][li] + red_q[1][li] + red_q[2][li] + red_q[3][li];
    float m = ts * (1.f / 128.f);
    float var = tq * (1.f / 128.f) - m * m;
    mu[ni] = m;
    rstd[ni] = rsqrtf(var + 1e-5f);
  }
  float* ob = out + (size_t)b * 128 * L_N;
#pragma unroll
  for (int mi = 0; mi < 2; ++mi)
#pragma unroll
    for (int r = 0; r < 4; ++r) {
      int o = o0 + mi * 16 + quad * 4 + r;
      float g = gs[o], bb = bs[o];
#pragma unroll
      for (int ni = 0; ni < 4; ++ni)
        ob[(size_t)o * L_N + l0 + ni * 16 + col] = (acc[mi][ni][r] - mu[ni]) * rstd[ni] * g + bb;
    }
}

// ---------------------------------------------------------------------------
extern "C" void kernel_launch(void* const* d_in, const int* in_sizes, int n_in,
                              void* d_out, int out_size, void* d_ws, size_t ws_size,
                              hipStream_t stream) {
  const float* x    = (const float*)d_in[0];
  const float* w1   = (const float*)d_in[1];
  const float* cw   = (const float*)d_in[2];
  const float* cb   = (const float*)d_in[3];
  const float* xpw  = (const float*)d_in[4];
  const float* dtw  = (const float*)d_in[5];
  const float* dtb  = (const float*)d_in[6];
  const float* alog = (const float*)d_in[7];
  const float* dpar = (const float*)d_in[8];
  const float* w2   = (const float*)d_in[9];
  const float* gam  = (const float*)d_in[10];
  const float* bet  = (const float*)d_in[11];
  float* out = (float*)d_out;

  float* ws = (float*)d_ws;
  const size_t NBL = (size_t)B_N * 128 * L_N;      // 18,874,368
  float* xdblT = ws;                                // fp32 (B,12,L)
  __hip_bfloat16* xt   = (__hip_bfloat16*)(ws + (size_t)B_N * 12 * L_N);
  __hip_bfloat16* xinb = xt + NBL;                  // bf16 (B,D,L)
  __hip_bfloat16* zb   = xinb + NBL;                // bf16 (B,D,L)
  __hip_bfloat16* yb   = zb + NBL;                  // bf16 (B,D,L)
  __hip_bfloat16* w1bt = yb + NBL;
  __hip_bfloat16* w2bt = w1bt + 256 * 128;

  k_prep<<<128, 256, 0, stream>>>(w1, w2, w1bt, w2bt);
  k_xt<<<B_N * LT64, 256, 0, stream>>>(x, xt);
  k_inproj_conv<<<B_N * LT64, 256, 0, stream>>>(xt, w1bt, cw, cb, xpw, xinb, zb, xdblT);
  k_scan<<<B_N * 128, 256, 0, stream>>>(xdblT, dtw, dtb, alog, dpar, xinb, zb, yb);
  k_outln<<<B_N * LT64, 256, 0, stream>>>(yb, w2bt, gam, bet, out);
}